// Round 5
// baseline (107.370 us; speedup 1.0000x reference)
//
#include <hip/hip_runtime.h>

#define NBLK 1024
#define NTHR 256
#define H1_BINS 2048
#define H1_SHIFT 20
#define NCOPY 4
#define H2_BINS (1u << H1_SHIFT)      // 1048576
#define H2_MASK (H2_BINS - 1u)
#define CHUNK 2048
#define NCHUNK ((int)(H2_BINS / CHUNK))   // 512

// ws layout (bytes):
//   CTRL     [0, 256)         u64[0]=posCount u64[1]=negCount u64[2]=b1 u64[3]=need
//                             u64[4]=k  dbl[5]=posLoss dbl[6]=totLoss
//   H1       [1024, 9216)            2048 x u32
//   p1part   [16384, 32768)          NBLK x 2 doubles
//   p2part   [32768, 40960)          NBLK doubles
//   chunkCnt [40960, 45056)          512 x u64
//   chunkW   [45056, 49152)          512 x double
//   H2       [65536, 4259840)        2^20 x u32
//   lossBits [4259840, +4n)          n x u32 (only if ws_size permits)
#define OFF_H1       1024
#define OFF_P1PART   16384
#define OFF_P2PART   32768
#define OFF_CCNT     40960
#define OFF_CW       45056
#define OFF_H2       65536
#define OFF_LOSS     4259840

#define LN2F 0.69314718055994531f

// loss = min(-log(x), 100) * m  with x = (t==0 ? p : 1-p); single v_log_f32.
__device__ __forceinline__ void elem_compute(float pp, int tt, float mm,
                                             float& loss, bool& pos, bool& neg) {
    bool isz = (tt == 0);
    float x = isz ? pp : (1.0f - pp);
    float lr = fminf(-__log2f(x) * LN2F, 100.0f);   // >= 0 always; log2(0) -> 100
    loss = lr * mm;
    float tm = isz ? mm : 0.0f;           // t * mask
    pos = (tm == 1.0f);
    neg = (tm == 0.0f);
}

template <bool STORE>
__global__ __launch_bounds__(NTHR) void pass1(const float* __restrict__ pred,
                                              const int* __restrict__ targ,
                                              const float* __restrict__ mask,
                                              int n, unsigned* __restrict__ gH1,
                                              unsigned long long* __restrict__ ctrl,
                                              double* __restrict__ p1part,
                                              unsigned* __restrict__ lossOut) {
    __shared__ unsigned shist[H1_BINS * NCOPY];   // 32 KB, interleaved copies
    __shared__ double sredd[NTHR];
    __shared__ unsigned sredu[NTHR];
    int tid = threadIdx.x;
    int copyIdx = tid & (NCOPY - 1);
    for (int i = tid; i < H1_BINS * NCOPY; i += NTHR) shist[i] = 0;
    __syncthreads();

    float posLoss = 0.f, totLoss = 0.f;
    unsigned posCnt = 0, negCnt = 0;

    int nv = n >> 2;
    int gstride = gridDim.x * blockDim.x;
    int g0 = blockIdx.x * blockDim.x + tid;
    const float4* p4 = (const float4*)pred;
    const int4*   t4 = (const int4*)targ;
    const float4* m4 = (const float4*)mask;
    uint4* l4 = (uint4*)lossOut;
    for (int i = g0; i < nv; i += gstride) {
        float4 p = p4[i]; int4 t = t4[i]; float4 m = m4[i];
        float pa[4] = {p.x, p.y, p.z, p.w};
        int   ta[4] = {t.x, t.y, t.z, t.w};
        float ma[4] = {m.x, m.y, m.z, m.w};
        unsigned ua[4];
        #pragma unroll
        for (int j = 0; j < 4; ++j) {
            float loss; bool pos, neg;
            elem_compute(pa[j], ta[j], ma[j], loss, pos, neg);
            totLoss += loss;
            if (pos) { posCnt++; posLoss += loss; }
            unsigned u = __float_as_uint(loss);
            if (u & 0x80000000u) u = 0u;   // -0 -> 0
            if (neg) {
                negCnt++;
                atomicAdd(&shist[(u >> H1_SHIFT) * NCOPY + copyIdx], 1u);
            } else {
                u = 0x80000000u;           // sentinel: not a negative
            }
            ua[j] = u;
        }
        if (STORE) {
            uint4 st; st.x = ua[0]; st.y = ua[1]; st.z = ua[2]; st.w = ua[3];
            l4[i] = st;
        }
    }
    for (int i = (nv << 2) + g0; i < n; i += gstride) {
        float loss; bool pos, neg;
        elem_compute(pred[i], targ[i], mask[i], loss, pos, neg);
        totLoss += loss;
        if (pos) { posCnt++; posLoss += loss; }
        unsigned u = __float_as_uint(loss);
        if (u & 0x80000000u) u = 0u;
        if (neg) {
            negCnt++;
            atomicAdd(&shist[(u >> H1_SHIFT) * NCOPY + copyIdx], 1u);
        } else {
            u = 0x80000000u;
        }
        if (STORE) lossOut[i] = u;
    }
    __syncthreads();
    // merge copies -> global (skip empty bins); one b128 read per bin
    for (int b = tid; b < H1_BINS; b += NTHR) {
        uint4 v = *(const uint4*)&shist[b * NCOPY];
        unsigned c = v.x + v.y + v.z + v.w;
        if (c) atomicAdd(&gH1[b], c);
    }
    // deterministic block reductions
    sredd[tid] = (double)posLoss; __syncthreads();
    for (int s = NTHR / 2; s > 0; s >>= 1) { if (tid < s) sredd[tid] += sredd[tid + s]; __syncthreads(); }
    if (tid == 0) p1part[2 * blockIdx.x] = sredd[0];
    __syncthreads();
    sredd[tid] = (double)totLoss; __syncthreads();
    for (int s = NTHR / 2; s > 0; s >>= 1) { if (tid < s) sredd[tid] += sredd[tid + s]; __syncthreads(); }
    if (tid == 0) p1part[2 * blockIdx.x + 1] = sredd[0];
    __syncthreads();
    sredu[tid] = posCnt; __syncthreads();
    for (int s = NTHR / 2; s > 0; s >>= 1) { if (tid < s) sredu[tid] += sredu[tid + s]; __syncthreads(); }
    if (tid == 0) atomicAdd(&ctrl[0], (unsigned long long)sredu[0]);
    __syncthreads();
    sredu[tid] = negCnt; __syncthreads();
    for (int s = NTHR / 2; s > 0; s >>= 1) { if (tid < s) sredu[tid] += sredu[tid + s]; __syncthreads(); }
    if (tid == 0) atomicAdd(&ctrl[1], (unsigned long long)sredu[0]);
}

__global__ __launch_bounds__(1024) void findbin(const unsigned* __restrict__ gH1,
                                                unsigned long long* __restrict__ ctrl,
                                                const double* __restrict__ p1part) {
    __shared__ double sd[1024];
    __shared__ unsigned long long ss[1024];
    int tid = threadIdx.x;
    sd[tid] = p1part[2 * tid]; __syncthreads();
    for (int s = 512; s > 0; s >>= 1) { if (tid < s) sd[tid] += sd[tid + s]; __syncthreads(); }
    double posLoss = sd[0]; __syncthreads();
    sd[tid] = p1part[2 * tid + 1]; __syncthreads();
    for (int s = 512; s > 0; s >>= 1) { if (tid < s) sd[tid] += sd[tid + s]; __syncthreads(); }
    double totLoss = sd[0]; __syncthreads();

    unsigned long long posCnt = ctrl[0];
    unsigned long long negCnt = ctrl[1];
    unsigned long long k = posCnt * 5ULL;
    if (k > negCnt) k = negCnt;

    // suffix scan of 2048-bin histogram (2 bins / thread)
    int base = tid * 2;
    unsigned h0 = gH1[base], h1 = gH1[base + 1];
    ss[tid] = (unsigned long long)h0 + h1; __syncthreads();
    for (int d = 1; d < 1024; d <<= 1) {
        unsigned long long add = (tid + d < 1024) ? ss[tid + d] : 0ULL;
        __syncthreads();
        ss[tid] += add;
        __syncthreads();
    }
    unsigned long long run = (tid == 1023) ? 0ULL : ss[tid + 1];
    if (k > 0) {
        // walk own bins, higher first
        if (run < k && k <= run + h1) {
            ctrl[2] = (unsigned long long)(base + 1);
            ctrl[3] = k - run;
        }
        run += h1;
        if (run < k && k <= run + h0) {
            ctrl[2] = (unsigned long long)base;
            ctrl[3] = k - run;
        }
    } else if (tid == 0) {
        ctrl[2] = (unsigned long long)H1_BINS;  // sentinel: no selection
        ctrl[3] = 0;
    }
    if (tid == 0) {
        ctrl[4] = k;
        ((double*)ctrl)[5] = posLoss;
        ((double*)ctrl)[6] = totLoss;
    }
}

// pass2 from stored loss bits (64 MB read, no recompute)
__global__ __launch_bounds__(NTHR) void pass2s(const unsigned* __restrict__ lossBits,
                                               int n,
                                               const unsigned long long* __restrict__ ctrl,
                                               unsigned* __restrict__ gH2,
                                               double* __restrict__ p2part) {
    __shared__ double sredd[NTHR];
    int tid = threadIdx.x;
    unsigned b1 = (unsigned)ctrl[2];
    float acc = 0.f;
    int nv = n >> 2;
    int gstride = gridDim.x * blockDim.x;
    int g0 = blockIdx.x * blockDim.x + tid;
    const uint4* l4 = (const uint4*)lossBits;
    for (int i = g0; i < nv; i += gstride) {
        uint4 v = l4[i];
        unsigned ua[4] = {v.x, v.y, v.z, v.w};
        #pragma unroll
        for (int j = 0; j < 4; ++j) {
            unsigned u = ua[j];
            if (!(u & 0x80000000u)) {
                unsigned bin = u >> H1_SHIFT;
                if (bin > b1) acc += __uint_as_float(u);
                else if (bin == b1) atomicAdd(&gH2[u & H2_MASK], 1u);
            }
        }
    }
    for (int i = (nv << 2) + g0; i < n; i += gstride) {
        unsigned u = lossBits[i];
        if (!(u & 0x80000000u)) {
            unsigned bin = u >> H1_SHIFT;
            if (bin > b1) acc += __uint_as_float(u);
            else if (bin == b1) atomicAdd(&gH2[u & H2_MASK], 1u);
        }
    }
    sredd[tid] = (double)acc; __syncthreads();
    for (int s = NTHR / 2; s > 0; s >>= 1) { if (tid < s) sredd[tid] += sredd[tid + s]; __syncthreads(); }
    if (tid == 0) p2part[blockIdx.x] = sredd[0];
}

// fallback pass2: recompute losses from inputs
__global__ __launch_bounds__(NTHR) void pass2(const float* __restrict__ pred,
                                              const int* __restrict__ targ,
                                              const float* __restrict__ mask,
                                              int n,
                                              const unsigned long long* __restrict__ ctrl,
                                              unsigned* __restrict__ gH2,
                                              double* __restrict__ p2part) {
    __shared__ double sredd[NTHR];
    int tid = threadIdx.x;
    unsigned b1 = (unsigned)ctrl[2];
    float acc = 0.f;
    int nv = n >> 2;
    int gstride = gridDim.x * blockDim.x;
    int g0 = blockIdx.x * blockDim.x + tid;
    const float4* p4 = (const float4*)pred;
    const int4*   t4 = (const int4*)targ;
    const float4* m4 = (const float4*)mask;
    for (int i = g0; i < nv; i += gstride) {
        float4 p = p4[i]; int4 t = t4[i]; float4 m = m4[i];
        float pa[4] = {p.x, p.y, p.z, p.w};
        int   ta[4] = {t.x, t.y, t.z, t.w};
        float ma[4] = {m.x, m.y, m.z, m.w};
        #pragma unroll
        for (int j = 0; j < 4; ++j) {
            float loss; bool pos, neg;
            elem_compute(pa[j], ta[j], ma[j], loss, pos, neg);
            if (neg) {
                unsigned u = __float_as_uint(loss);
                if (u & 0x80000000u) u = 0u;
                unsigned bin = u >> H1_SHIFT;
                if (bin > b1) acc += loss;
                else if (bin == b1) atomicAdd(&gH2[u & H2_MASK], 1u);
            }
        }
    }
    for (int i = (nv << 2) + g0; i < n; i += gstride) {
        float loss; bool pos, neg;
        elem_compute(pred[i], targ[i], mask[i], loss, pos, neg);
        if (neg) {
            unsigned u = __float_as_uint(loss);
            if (u & 0x80000000u) u = 0u;
            unsigned bin = u >> H1_SHIFT;
            if (bin > b1) acc += loss;
            else if (bin == b1) atomicAdd(&gH2[u & H2_MASK], 1u);
        }
    }
    sredd[tid] = (double)acc; __syncthreads();
    for (int s = NTHR / 2; s > 0; s >>= 1) { if (tid < s) sredd[tid] += sredd[tid + s]; __syncthreads(); }
    if (tid == 0) p2part[blockIdx.x] = sredd[0];
}

__global__ __launch_bounds__(256) void chunkscan(const unsigned* __restrict__ gH2,
                                                 const unsigned long long* __restrict__ ctrl,
                                                 unsigned long long* __restrict__ chunkCnt,
                                                 double* __restrict__ chunkW) {
    __shared__ unsigned long long sc[256];
    __shared__ double sw[256];
    int tid = threadIdx.x;
    unsigned b1 = (unsigned)ctrl[2];
    int base = blockIdx.x * CHUNK;
    unsigned long long cnt = 0; double w = 0.0;
    if (b1 < H1_BINS) {
        for (int i = tid; i < CHUNK; i += 256) {
            unsigned c = gH2[base + i];
            if (c) {
                float L = __uint_as_float((b1 << H1_SHIFT) | (unsigned)(base + i));
                cnt += c;
                w += (double)c * (double)L;
            }
        }
    }
    sc[tid] = cnt; sw[tid] = w; __syncthreads();
    for (int s = 128; s > 0; s >>= 1) {
        if (tid < s) { sc[tid] += sc[tid + s]; sw[tid] += sw[tid + s]; }
        __syncthreads();
    }
    if (tid == 0) { chunkCnt[blockIdx.x] = sc[0]; chunkW[blockIdx.x] = sw[0]; }
}

__global__ __launch_bounds__(512) void finalize(const unsigned* __restrict__ gH2,
                                                const unsigned long long* __restrict__ ctrl,
                                                const double* __restrict__ p2part,
                                                const unsigned long long* __restrict__ chunkCnt,
                                                const double* __restrict__ chunkW,
                                                float* __restrict__ out, int n) {
    __shared__ double sd[512];
    __shared__ unsigned long long sc[512];
    __shared__ double sw[512];
    __shared__ int s_cstar;
    __shared__ unsigned long long s_rem;
    __shared__ double s_wAbove;
    __shared__ double s_res;
    int tid = threadIdx.x;

    sd[tid] = p2part[tid] + p2part[tid + 512]; __syncthreads();
    for (int s = 256; s > 0; s >>= 1) { if (tid < s) sd[tid] += sd[tid + s]; __syncthreads(); }
    double sumAbove = sd[0]; __syncthreads();

    unsigned long long posCnt = ctrl[0];
    unsigned long long b1 = ctrl[2];
    unsigned long long need = ctrl[3];
    unsigned long long k = ctrl[4];
    double posLoss = ((const double*)ctrl)[5];
    double totLoss = ((const double*)ctrl)[6];

    double negLoss = sumAbove;

    if (need > 0) {
        if (tid == 0) { s_cstar = 0; s_rem = 1; s_wAbove = 0.0; s_res = 0.0; }
        // stage 1: suffix scan over 512 chunks
        unsigned long long myc = chunkCnt[tid];
        double myw = chunkW[tid];
        sc[tid] = myc; sw[tid] = myw; __syncthreads();
        for (int d = 1; d < 512; d <<= 1) {
            unsigned long long ac = (tid + d < 512) ? sc[tid + d] : 0ULL;
            double aw = (tid + d < 512) ? sw[tid + d] : 0.0;
            __syncthreads();
            sc[tid] += ac; sw[tid] += aw;
            __syncthreads();
        }
        unsigned long long afterC = (tid == 511) ? 0ULL : sc[tid + 1];
        double afterW = (tid == 511) ? 0.0 : sw[tid + 1];
        if (afterC < need && need <= afterC + myc) {
            s_cstar = tid; s_rem = need - afterC; s_wAbove = afterW;
        }
        __syncthreads();
        int cstar = s_cstar;
        unsigned long long rem = s_rem;
        double wAbove = s_wAbove;
        __syncthreads();

        // stage 2: within chunk cstar (2048 patterns), 4 per thread
        int pb = cstar * CHUNK + 4 * tid;
        unsigned c[4]; double L[4];
        unsigned long long tot = 0; double wtot = 0.0;
        #pragma unroll
        for (int j = 0; j < 4; ++j) {
            c[j] = gH2[pb + j];
            L[j] = (double)__uint_as_float(((unsigned)b1 << H1_SHIFT) | (unsigned)(pb + j));
            tot += c[j];
            wtot += (double)c[j] * L[j];
        }
        sc[tid] = tot; sw[tid] = wtot;
        __syncthreads();
        for (int d = 1; d < 512; d <<= 1) {
            unsigned long long ac = (tid + d < 512) ? sc[tid + d] : 0ULL;
            double aw = (tid + d < 512) ? sw[tid + d] : 0.0;
            __syncthreads();
            sc[tid] += ac; sw[tid] += aw;
            __syncthreads();
        }
        unsigned long long run = (tid == 511) ? 0ULL : sc[tid + 1];
        double wrun = (tid == 511) ? 0.0 : sw[tid + 1];
        // walk own 4 patterns, higher value (higher index) first
        #pragma unroll
        for (int j = 3; j >= 0; --j) {
            if (run < rem && rem <= run + c[j]) {
                s_res = wrun + (double)(rem - run) * L[j];
            }
            run += c[j];
            wrun += (double)c[j] * L[j];
        }
        __syncthreads();
        negLoss += wAbove + s_res;
    }

    if (tid == 0) {
        double result;
        if (posCnt == 0) {
            result = totLoss / (double)n;
        } else {
            result = (posLoss + negLoss) / ((double)posCnt + (double)k + 1e-8);
        }
        out[0] = (float)result;
    }
}

extern "C" void kernel_launch(void* const* d_in, const int* in_sizes, int n_in,
                              void* d_out, int out_size, void* d_ws, size_t ws_size,
                              hipStream_t stream) {
    const float* pred = (const float*)d_in[0];
    const int*   targ = (const int*)d_in[1];
    const float* mask = (const float*)d_in[2];
    int n = in_sizes[0];

    char* ws = (char*)d_ws;
    unsigned long long* ctrl = (unsigned long long*)ws;
    unsigned* gH1 = (unsigned*)(ws + OFF_H1);
    double* p1part = (double*)(ws + OFF_P1PART);
    double* p2part = (double*)(ws + OFF_P2PART);
    unsigned long long* chunkCnt = (unsigned long long*)(ws + OFF_CCNT);
    double* chunkW = (double*)(ws + OFF_CW);
    unsigned* gH2 = (unsigned*)(ws + OFF_H2);
    unsigned* lossBits = (unsigned*)(ws + OFF_LOSS);

    bool store = ws_size >= (size_t)OFF_LOSS + (size_t)n * 4ull;

    hipMemsetAsync(ws, 0, OFF_H1 + H1_BINS * 4, stream);           // ctrl + H1
    hipMemsetAsync(ws + OFF_H2, 0, H2_BINS * 4, stream);           // H2

    if (store) {
        pass1<true><<<NBLK, NTHR, 0, stream>>>(pred, targ, mask, n, gH1, ctrl, p1part, lossBits);
        findbin<<<1, 1024, 0, stream>>>(gH1, ctrl, p1part);
        pass2s<<<NBLK, NTHR, 0, stream>>>(lossBits, n, ctrl, gH2, p2part);
    } else {
        pass1<false><<<NBLK, NTHR, 0, stream>>>(pred, targ, mask, n, gH1, ctrl, p1part, lossBits);
        findbin<<<1, 1024, 0, stream>>>(gH1, ctrl, p1part);
        pass2<<<NBLK, NTHR, 0, stream>>>(pred, targ, mask, n, ctrl, gH2, p2part);
    }
    chunkscan<<<NCHUNK, 256, 0, stream>>>(gH2, ctrl, chunkCnt, chunkW);
    finalize<<<1, 512, 0, stream>>>(gH2, ctrl, p2part, chunkCnt, chunkW, (float*)d_out, n);
}